// Round 1
// baseline (377.163 us; speedup 1.0000x reference)
//
#include <hip/hip_runtime.h>
#include <math.h>

// Problem constants (from reference)
#define NNODES 100000
#define NEDGES 500000
#define HID    256      // hidden
#define K2     512      // 2*HID
#define BM     64       // edges per block
#define NBLK   ((NEDGES + BM - 1) / BM)   // 7813

typedef __bf16 bf16x8 __attribute__((ext_vector_type(8)));
typedef float  f32x4  __attribute__((ext_vector_type(4)));

// float -> bf16 round-to-nearest-even (payload as ushort)
__device__ __forceinline__ unsigned short f2bf(float f) {
    unsigned int u = __float_as_uint(f);
    u += 0x7FFFu + ((u >> 16) & 1u);
    return (unsigned short)(u >> 16);
}

// ---------------- x fp32 -> bf16 (25.6M elems, 8 per thread) ----------------
__global__ void cvt_x_kernel(const float* __restrict__ x, unsigned short* __restrict__ xb) {
    long i = (long)blockIdx.x * 256 + threadIdx.x;          // one 8-elem chunk
    if (i >= (long)NNODES * (HID / 8)) return;
    const float4* p = (const float4*)x + i * 2;
    float4 a = p[0], b = p[1];
    union { unsigned short s[8]; uint4 v; } u;
    u.s[0] = f2bf(a.x); u.s[1] = f2bf(a.y); u.s[2] = f2bf(a.z); u.s[3] = f2bf(a.w);
    u.s[4] = f2bf(b.x); u.s[5] = f2bf(b.y); u.s[6] = f2bf(b.z); u.s[7] = f2bf(b.w);
    ((uint4*)xb)[i] = u.v;
}

// ------------- W1 [256][512] fp32 -> Bsw bf16, MFMA-B-fragment order ---------
// Bsw unit t=(kt*16+nt)*64+lane holds 8 bf16: B[k=kt*32+(lane>>4)*8+j][n=nt*16+(lane&15)]
// where B[k][n] = W1[n][k]. So a wave's B-frag load is one coalesced dwordx4/lane.
__global__ void cvt_w1_kernel(const float* __restrict__ W1, unsigned short* __restrict__ Bsw) {
    int t = blockIdx.x * 256 + threadIdx.x;                  // 16*16*64 = 16384 units
    if (t >= 16 * 16 * 64) return;
    int lane = t & 63, nt = (t >> 6) & 15, kt = t >> 10;
    int n = nt * 16 + (lane & 15);
    int k = kt * 32 + ((lane >> 4) << 3);
    const float* src = W1 + (size_t)n * K2 + k;              // 8 consecutive
    union { unsigned short s[8]; uint4 v; } u;
#pragma unroll
    for (int j = 0; j < 8; ++j) u.s[j] = f2bf(src[j]);
    ((uint4*)Bsw)[t] = u.v;
}

// ---------------------------- fused edge MLP --------------------------------
// Block = 256 threads = 4 waves; 64 edges/block; wave w owns N-cols [w*64, w*64+64).
// A (gathered concat features) staged per-K-half (256) into LDS in fragment-
// swizzled 16B units: unit u = (kt_local*4 + mt)*64 + (q*16 + mlow), XORed by
// (u>>8)&7 to spread LDS banks on the write side (reads are lane-sequential).
template <bool USEBF>
__global__ __launch_bounds__(256) void edge_mlp_kernel(
    const unsigned short* __restrict__ xb,   // [NNODES][256] bf16 (if USEBF)
    const float* __restrict__ xf,            // [NNODES][256] fp32 (fallback)
    const int* __restrict__ ei,              // [2][NEDGES]
    const unsigned short* __restrict__ Bsw,  // swizzled W1^T bf16
    const float* __restrict__ b1,            // [256]
    const float* __restrict__ W2,            // [256]
    const float* __restrict__ b2,            // [1]
    float* __restrict__ out)                 // [NEDGES]
{
    __shared__ __align__(16) unsigned short Asw[8 * 4 * 64 * 8];  // 32 KB: one K-half
    __shared__ float es[BM];

    const int tid  = threadIdx.x;
    const int lane = tid & 63;
    const int wave = tid >> 6;
    const int e0   = blockIdx.x * BM;

    if (tid < BM) es[tid] = 0.0f;

    f32x4 acc[4][4] = {};   // [mt][nt], D-layout: row=quad*4+r (M), col=lane&15 (N)

    const bf16x8* A8 = (const bf16x8*)Asw;
    const bf16x8* B8 = (const bf16x8*)Bsw;

    for (int h = 0; h < 2; ++h) {           // K halves: h=0 src feats, h=1 dst feats
        // ---- stage: 64 edges x 256 elems; wave covers 2 edges/iter ----
#pragma unroll
        for (int i = 0; i < 8; ++i) {
            int m  = i * 8 + wave * 2 + (lane >> 5);        // 0..63, each once
            int e  = e0 + m;
            int ee = (e < NEDGES) ? e : 0;
            int node  = ei[(size_t)h * NEDGES + ee];
            int chunk = lane & 31;                           // 8-elem chunk in row
            uint4 v;
            if constexpr (USEBF) {
                v = *((const uint4*)(xb + ((size_t)node << 8) + (chunk << 3)));
            } else {
                const float4* p = (const float4*)(xf + ((size_t)node << 8) + (chunk << 3));
                float4 a = p[0], bq = p[1];
                union { unsigned short s[8]; uint4 v4; } u;
                u.s[0] = f2bf(a.x);  u.s[1] = f2bf(a.y);  u.s[2] = f2bf(a.z);  u.s[3] = f2bf(a.w);
                u.s[4] = f2bf(bq.x); u.s[5] = f2bf(bq.y); u.s[6] = f2bf(bq.z); u.s[7] = f2bf(bq.w);
                v = u.v4;
            }
            int ktl = chunk >> 2;                            // local kt 0..7
            int q   = chunk & 3;
            int u16 = ((ktl * 4 + (m >> 4)) << 6) + (q << 4) + (m & 15);
            u16 ^= (u16 >> 8) & 7;                           // bank swizzle
            ((uint4*)Asw)[u16] = v;
        }
        __syncthreads();

        // ---- compute: 8 local K-steps of 32 ----
#pragma unroll
        for (int kt = 0; kt < 8; ++kt) {
            bf16x8 af[4];
#pragma unroll
            for (int mt = 0; mt < 4; ++mt) {
                int u16 = ((kt * 4 + mt) << 6) + lane;
                u16 ^= (u16 >> 8) & 7;
                af[mt] = A8[u16];
            }
            bf16x8 bfr[4];
#pragma unroll
            for (int nt = 0; nt < 4; ++nt) {
                int ng = (wave << 2) + nt;                   // global N-tile 0..15
                bfr[nt] = B8[(((h * 8 + kt) << 4) + ng) * 64 + lane];
            }
#pragma unroll
            for (int mt = 0; mt < 4; ++mt)
#pragma unroll
                for (int nt = 0; nt < 4; ++nt)
                    acc[mt][nt] = __builtin_amdgcn_mfma_f32_16x16x32_bf16(
                        af[mt], bfr[nt], acc[mt][nt], 0, 0, 0);
        }
        __syncthreads();
    }

    // ---- epilogue: relu(acc + b1) . W2, reduce over N, sigmoid ----
    float w2v[4], b1v[4];
#pragma unroll
    for (int nt = 0; nt < 4; ++nt) {
        int n = (wave << 6) + (nt << 4) + (lane & 15);
        w2v[nt] = W2[n];
        b1v[nt] = b1[n];
    }
#pragma unroll
    for (int mt = 0; mt < 4; ++mt) {
#pragma unroll
        for (int r = 0; r < 4; ++r) {
            float p = 0.0f;
#pragma unroll
            for (int nt = 0; nt < 4; ++nt) {
                float hv = acc[mt][nt][r] + b1v[nt];
                p = fmaf(fmaxf(hv, 0.0f), w2v[nt], p);
            }
            // sum over the 16 lanes of this quad (same edge, different n)
            p += __shfl_xor(p, 1, 16);
            p += __shfl_xor(p, 2, 16);
            p += __shfl_xor(p, 4, 16);
            p += __shfl_xor(p, 8, 16);
            if ((lane & 15) == 0) {
                int m = (mt << 4) + ((lane >> 4) << 2) + r;
                atomicAdd(&es[m], p);                        // cross-wave (4 N-slices)
            }
        }
    }
    __syncthreads();

    if (tid < BM) {
        int e = e0 + tid;
        if (e < NEDGES) {
            float z = es[tid] + b2[0];
            out[e] = 1.0f / (1.0f + expf(-z));
        }
    }
}

extern "C" void kernel_launch(void* const* d_in, const int* in_sizes, int n_in,
                              void* d_out, int out_size, void* d_ws, size_t ws_size,
                              hipStream_t stream) {
    const float* x  = (const float*)d_in[0];
    const int*   ei = (const int*)d_in[1];
    const float* W1 = (const float*)d_in[2];
    const float* b1 = (const float*)d_in[3];
    const float* W2 = (const float*)d_in[4];
    const float* b2 = (const float*)d_in[5];
    float* out = (float*)d_out;

    unsigned short* Bsw = (unsigned short*)d_ws;                     // 256 KB
    unsigned short* xb  = (unsigned short*)((char*)d_ws + (1 << 18)); // 51.2 MB

    const size_t need_xb = (size_t)(1 << 18) + (size_t)NNODES * HID * 2 + 1024;

    cvt_w1_kernel<<<64, 256, 0, stream>>>(W1, Bsw);
    if (ws_size >= need_xb) {
        cvt_x_kernel<<<(NNODES * (HID / 8) + 255) / 256, 256, 0, stream>>>(x, xb);
        edge_mlp_kernel<true><<<NBLK, 256, 0, stream>>>(xb, x, ei, Bsw, b1, W2, b2, out);
    } else {
        // workspace too small for bf16 x copy: gather fp32 and convert in-kernel
        edge_mlp_kernel<false><<<NBLK, 256, 0, stream>>>(nullptr, x, ei, Bsw, b1, W2, b2, out);
    }
}

// Round 2
// 298.451 us; speedup vs baseline: 1.2637x; 1.2637x over previous
//
#include <hip/hip_runtime.h>
#include <math.h>

// Problem constants
#define NNODES 100000
#define NODESP 100096            // padded to 782*128 for GEMM M-tiles
#define NEDGES 500000
#define HID    256
#define K2     512

typedef __bf16 bf16x8 __attribute__((ext_vector_type(8)));
typedef float  f32x4  __attribute__((ext_vector_type(4)));

__device__ __forceinline__ unsigned short f2bf(float f) {
    unsigned int u = __float_as_uint(f);
    u += 0x7FFFu + ((u >> 16) & 1u);
    return (unsigned short)(u >> 16);
}
__device__ __forceinline__ float bf2f(unsigned short s) {
    return __uint_as_float(((unsigned int)s) << 16);
}
__device__ __forceinline__ void async16(void* lds, const void* g) {
    __builtin_amdgcn_global_load_lds((const __attribute__((address_space(1))) void*)g,
                                     (__attribute__((address_space(3))) void*)lds, 16, 0, 0);
}

// ---------------- x fp32 -> bf16, padded to NODESP rows (zeros past NNODES) --
__global__ void cvt_x_pad(const float* __restrict__ x, unsigned short* __restrict__ xb) {
    long i = (long)blockIdx.x * 256 + threadIdx.x;          // one 8-elem chunk
    if (i >= (long)NODESP * (HID / 8)) return;
    uint4 outv = make_uint4(0, 0, 0, 0);
    if (i < (long)NNODES * (HID / 8)) {
        const float4* p = (const float4*)x + i * 2;
        float4 a = p[0], b = p[1];
        union { unsigned short s[8]; uint4 v; } u;
        u.s[0] = f2bf(a.x); u.s[1] = f2bf(a.y); u.s[2] = f2bf(a.z); u.s[3] = f2bf(a.w);
        u.s[4] = f2bf(b.x); u.s[5] = f2bf(b.y); u.s[6] = f2bf(b.z); u.s[7] = f2bf(b.w);
        outv = u.v;
    }
    ((uint4*)xb)[i] = outv;
}

// ---- W1 [256][512] fp32 -> Bsw bf16 fragment order for node GEMM (K=256,N=512)
// B[k][j] = W1[j&255][(j>=256?256:0)+k].  Unit t=(kt*32+nt)*64+lane holds 8 bf16
// along k: k = kt*32+(lane>>4)*8+jj, j = nt*16+(lane&15).
__global__ void cvt_w1uv(const float* __restrict__ W1, unsigned short* __restrict__ Bsw) {
    int t = blockIdx.x * 256 + threadIdx.x;                  // 8*32*64 = 16384 units
    if (t >= 8 * 32 * 64) return;
    int lane = t & 63, nt = (t >> 6) & 31, kt = t >> 11;
    int j = nt * 16 + (lane & 15);                           // 0..511
    int k = kt * 32 + ((lane >> 4) << 3);                    // 0..255
    const float* src = W1 + (size_t)(j & 255) * K2 + ((j >> 8) << 8) + k;
    union { unsigned short s[8]; uint4 v; } u;
#pragma unroll
    for (int jj = 0; jj < 8; ++jj) u.s[jj] = f2bf(src[jj]);
    ((uint4*)Bsw)[t] = u.v;
}

// ---------------- node GEMM: UV[n][j] = sum_k xb[n][k] * B[k][j] ------------
// M=NODESP, N=512, K=256. Block: 256 thr / 4 waves (2x2 over 128x128 tile).
// A staged via global_load_lds in fragment order (conflict-free, no ds_write).
// B fragments loaded directly from pre-swizzled Bsw (L2-resident).
__global__ __launch_bounds__(256) void node_gemm(
    const unsigned short* __restrict__ xb,
    const unsigned short* __restrict__ Bsw,
    unsigned short* __restrict__ UV)
{
    __shared__ __align__(16) unsigned short Asw[2048 * 8];   // 32 KB: K-half stage
    const int tid  = threadIdx.x;
    const int lane = tid & 63;
    const int wave = tid >> 6;
    const int wm   = wave >> 1, wn = wave & 1;
    const int m0   = blockIdx.x * 128;
    const int n0y  = blockIdx.y;                              // N-tile of 128

    f32x4 acc[4][4] = {};
    const bf16x8* A8 = (const bf16x8*)Asw;
    const bf16x8* B8 = (const bf16x8*)Bsw;
    uint4* A4 = (uint4*)Asw;

    for (int s = 0; s < 2; ++s) {                             // K-halves of 128
        // stage: 32 wave-instrs total, 8 per wave; LDS dest lane-sequential
#pragma unroll
        for (int i = 0; i < 8; ++i) {
            int w_idx = wave * 8 + i;                         // 0..31
            int mt_g  = w_idx & 7;                            // m-tile 0..7
            int ktl   = w_idx >> 3;                           // kt-in-stage 0..3
            int row   = m0 + mt_g * 16 + (lane & 15);
            int kelem = s * 128 + ktl * 32 + ((lane >> 4) << 3);
            async16(&A4[w_idx * 64], xb + (size_t)row * 256 + kelem);
        }
        __syncthreads();
#pragma unroll
        for (int ktl = 0; ktl < 4; ++ktl) {
            bf16x8 af[4], bfr[4];
#pragma unroll
            for (int mt = 0; mt < 4; ++mt)
                af[mt] = A8[(ktl * 8 + wm * 4 + mt) * 64 + lane];
#pragma unroll
            for (int nt = 0; nt < 4; ++nt) {
                int ng = n0y * 8 + wn * 4 + nt;               // n-tile 0..31
                bfr[nt] = B8[((s * 4 + ktl) * 32 + ng) * 64 + lane];
            }
#pragma unroll
            for (int mt = 0; mt < 4; ++mt)
#pragma unroll
                for (int nt = 0; nt < 4; ++nt)
                    acc[mt][nt] = __builtin_amdgcn_mfma_f32_16x16x32_bf16(
                        af[mt], bfr[nt], acc[mt][nt], 0, 0, 0);
        }
        __syncthreads();
    }
    // epilogue: store bf16
#pragma unroll
    for (int mt = 0; mt < 4; ++mt) {
#pragma unroll
        for (int nt = 0; nt < 4; ++nt) {
            int col = n0y * 128 + wn * 64 + nt * 16 + (lane & 15);
#pragma unroll
            for (int r = 0; r < 4; ++r) {
                int row = m0 + wm * 64 + mt * 16 + ((lane >> 4) << 2) + r;
                UV[(size_t)row * 512 + col] = f2bf(acc[mt][nt][r]);
            }
        }
    }
}

// ---------------- edge pass: gather u,v; relu; dot W2; sigmoid ---------------
// 32 lanes per edge (2 edges/wave). Lane q in [0,32): handles j = q*8..q*8+7.
__global__ __launch_bounds__(256) void edge_out(
    const unsigned short* __restrict__ UV,
    const int* __restrict__ ei,
    const float* __restrict__ b1,
    const float* __restrict__ W2,
    const float* __restrict__ b2,
    float* __restrict__ out)
{
    const int tid  = threadIdx.x;
    const int lane = tid & 63;
    const int wave = tid >> 6;
    const int q    = lane & 31;
    const int h    = lane >> 5;

    float b1v[8], w2v[8];
    {
        const float4* pb = (const float4*)b1 + q * 2;
        const float4* pw = (const float4*)W2 + q * 2;
        float4 a = pb[0], b = pb[1], c = pw[0], d = pw[1];
        b1v[0]=a.x; b1v[1]=a.y; b1v[2]=a.z; b1v[3]=a.w;
        b1v[4]=b.x; b1v[5]=b.y; b1v[6]=b.z; b1v[7]=b.w;
        w2v[0]=c.x; w2v[1]=c.y; w2v[2]=c.z; w2v[3]=c.w;
        w2v[4]=d.x; w2v[5]=d.y; w2v[6]=d.z; w2v[7]=d.w;
    }

    long e = (long)blockIdx.x * 8 + wave * 2 + h;
    if (e >= NEDGES) return;
    int src = ei[e];
    int dst = ei[NEDGES + e];

    union { uint4 v; unsigned short s[8]; } uu, vv;
    uu.v = *(const uint4*)(UV + (size_t)src * 512 + q * 8);
    vv.v = *(const uint4*)(UV + (size_t)dst * 512 + 256 + q * 8);

    float z = 0.0f;
#pragma unroll
    for (int jj = 0; jj < 8; ++jj) {
        float hv = bf2f(uu.s[jj]) + bf2f(vv.s[jj]) + b1v[jj];
        z = fmaf(fmaxf(hv, 0.0f), w2v[jj], z);
    }
    z += __shfl_xor(z, 1, 32);
    z += __shfl_xor(z, 2, 32);
    z += __shfl_xor(z, 4, 32);
    z += __shfl_xor(z, 8, 32);
    z += __shfl_xor(z, 16, 32);
    if (q == 0) out[e] = 1.0f / (1.0f + expf(-(z + b2[0])));
}

// ======================= round-1 fallback path ==============================
__global__ void cvt_x_r1(const float* __restrict__ x, unsigned short* __restrict__ xb) {
    long i = (long)blockIdx.x * 256 + threadIdx.x;
    if (i >= (long)NNODES * (HID / 8)) return;
    const float4* p = (const float4*)x + i * 2;
    float4 a = p[0], b = p[1];
    union { unsigned short s[8]; uint4 v; } u;
    u.s[0] = f2bf(a.x); u.s[1] = f2bf(a.y); u.s[2] = f2bf(a.z); u.s[3] = f2bf(a.w);
    u.s[4] = f2bf(b.x); u.s[5] = f2bf(b.y); u.s[6] = f2bf(b.z); u.s[7] = f2bf(b.w);
    ((uint4*)xb)[i] = u.v;
}

__global__ void cvt_w1_r1(const float* __restrict__ W1, unsigned short* __restrict__ Bsw) {
    int t = blockIdx.x * 256 + threadIdx.x;
    if (t >= 16 * 16 * 64) return;
    int lane = t & 63, nt = (t >> 6) & 15, kt = t >> 10;
    int n = nt * 16 + (lane & 15);
    int k = kt * 32 + ((lane >> 4) << 3);
    const float* src = W1 + (size_t)n * K2 + k;
    union { unsigned short s[8]; uint4 v; } u;
#pragma unroll
    for (int j = 0; j < 8; ++j) u.s[j] = f2bf(src[j]);
    ((uint4*)Bsw)[t] = u.v;
}

template <bool USEBF>
__global__ __launch_bounds__(256) void edge_mlp_kernel(
    const unsigned short* __restrict__ xb, const float* __restrict__ xf,
    const int* __restrict__ ei, const unsigned short* __restrict__ Bsw,
    const float* __restrict__ b1, const float* __restrict__ W2,
    const float* __restrict__ b2, float* __restrict__ out)
{
    __shared__ __align__(16) unsigned short Asw[8 * 4 * 64 * 8];
    __shared__ float es[64];
    const int tid = threadIdx.x, lane = tid & 63, wave = tid >> 6;
    const int e0 = blockIdx.x * 64;
    if (tid < 64) es[tid] = 0.0f;
    f32x4 acc[4][4] = {};
    const bf16x8* A8 = (const bf16x8*)Asw;
    const bf16x8* B8 = (const bf16x8*)Bsw;
    for (int h = 0; h < 2; ++h) {
#pragma unroll
        for (int i = 0; i < 8; ++i) {
            int m = i * 8 + wave * 2 + (lane >> 5);
            int e = e0 + m;
            int ee = (e < NEDGES) ? e : 0;
            int node = ei[(size_t)h * NEDGES + ee];
            int chunk = lane & 31;
            uint4 v;
            if constexpr (USEBF) {
                v = *((const uint4*)(xb + ((size_t)node << 8) + (chunk << 3)));
            } else {
                const float4* p = (const float4*)(xf + ((size_t)node << 8) + (chunk << 3));
                float4 a = p[0], bq = p[1];
                union { unsigned short s[8]; uint4 v4; } u;
                u.s[0] = f2bf(a.x);  u.s[1] = f2bf(a.y);  u.s[2] = f2bf(a.z);  u.s[3] = f2bf(a.w);
                u.s[4] = f2bf(bq.x); u.s[5] = f2bf(bq.y); u.s[6] = f2bf(bq.z); u.s[7] = f2bf(bq.w);
                v = u.v4;
            }
            int ktl = chunk >> 2, qq = chunk & 3;
            int u16 = ((ktl * 4 + (m >> 4)) << 6) + (qq << 4) + (m & 15);
            u16 ^= (u16 >> 8) & 7;
            ((uint4*)Asw)[u16] = v;
        }
        __syncthreads();
#pragma unroll
        for (int kt = 0; kt < 8; ++kt) {
            bf16x8 af[4], bfr[4];
#pragma unroll
            for (int mt = 0; mt < 4; ++mt) {
                int u16 = ((kt * 4 + mt) << 6) + lane;
                u16 ^= (u16 >> 8) & 7;
                af[mt] = A8[u16];
            }
#pragma unroll
            for (int nt = 0; nt < 4; ++nt)
                bfr[nt] = B8[(((h * 8 + kt) << 4) + (wave << 2) + nt) * 64 + lane];
#pragma unroll
            for (int mt = 0; mt < 4; ++mt)
#pragma unroll
                for (int nt = 0; nt < 4; ++nt)
                    acc[mt][nt] = __builtin_amdgcn_mfma_f32_16x16x32_bf16(
                        af[mt], bfr[nt], acc[mt][nt], 0, 0, 0);
        }
        __syncthreads();
    }
    float w2v[4], b1v[4];
#pragma unroll
    for (int nt = 0; nt < 4; ++nt) {
        int n = (wave << 6) + (nt << 4) + (lane & 15);
        w2v[nt] = W2[n]; b1v[nt] = b1[n];
    }
#pragma unroll
    for (int mt = 0; mt < 4; ++mt) {
#pragma unroll
        for (int r = 0; r < 4; ++r) {
            float p = 0.0f;
#pragma unroll
            for (int nt = 0; nt < 4; ++nt) {
                float hv = acc[mt][nt][r] + b1v[nt];
                p = fmaf(fmaxf(hv, 0.0f), w2v[nt], p);
            }
            p += __shfl_xor(p, 1, 16);
            p += __shfl_xor(p, 2, 16);
            p += __shfl_xor(p, 4, 16);
            p += __shfl_xor(p, 8, 16);
            if ((lane & 15) == 0)
                atomicAdd(&es[(mt << 4) + ((lane >> 4) << 2) + r], p);
        }
    }
    __syncthreads();
    if (tid < 64) {
        int e = e0 + tid;
        if (e < NEDGES) out[e] = 1.0f / (1.0f + expf(-(es[tid] + b2[0])));
    }
}

// ============================== launch ======================================
extern "C" void kernel_launch(void* const* d_in, const int* in_sizes, int n_in,
                              void* d_out, int out_size, void* d_ws, size_t ws_size,
                              hipStream_t stream) {
    const float* x  = (const float*)d_in[0];
    const int*   ei = (const int*)d_in[1];
    const float* W1 = (const float*)d_in[2];
    const float* b1 = (const float*)d_in[3];
    const float* W2 = (const float*)d_in[4];
    const float* b2 = (const float*)d_in[5];
    float* out = (float*)d_out;

    const size_t BSW_BYTES = 1 << 18;                         // 256 KB
    const size_t XB_BYTES  = (size_t)NODESP * HID * 2;        // 51.25 MB
    const size_t UV_BYTES  = (size_t)NODESP * K2 * 2;         // 102.5 MB
    const size_t NEED_A = BSW_BYTES + XB_BYTES + UV_BYTES;    // ~154 MB
    const size_t NEED_B = BSW_BYTES + (size_t)NNODES * HID * 2 + 1024;

    unsigned short* Bsw = (unsigned short*)d_ws;
    unsigned short* xb  = (unsigned short*)((char*)d_ws + BSW_BYTES);
    unsigned short* UV  = (unsigned short*)((char*)d_ws + BSW_BYTES + XB_BYTES);

    if (ws_size >= NEED_A) {
        cvt_w1uv<<<64, 256, 0, stream>>>(W1, Bsw);
        cvt_x_pad<<<(NODESP * (HID / 8)) / 256, 256, 0, stream>>>(x, xb);
        node_gemm<<<dim3(NODESP / 128, 4), 256, 0, stream>>>(xb, Bsw, UV);
        edge_out<<<(NEDGES + 7) / 8, 256, 0, stream>>>(UV, ei, b1, W2, b2, out);
    } else if (ws_size >= NEED_B) {
        cvt_w1_r1<<<64, 256, 0, stream>>>(W1, Bsw);
        cvt_x_r1<<<(NNODES * (HID / 8) + 255) / 256, 256, 0, stream>>>(x, xb);
        edge_mlp_kernel<true><<<(NEDGES + 63) / 64, 256, 0, stream>>>(xb, x, ei, Bsw, b1, W2, b2, out);
    } else {
        cvt_w1_r1<<<64, 256, 0, stream>>>(W1, Bsw);
        edge_mlp_kernel<false><<<(NEDGES + 63) / 64, 256, 0, stream>>>(nullptr, x, ei, Bsw, b1, W2, b2, out);
    }
}

// Round 3
// 265.391 us; speedup vs baseline: 1.4212x; 1.1246x over previous
//
#include <hip/hip_runtime.h>
#include <math.h>

// Problem constants
#define NNODES 100000
#define MT     64
#define NTILES 1563                     // ceil(100000/64)
#define NODESP (NTILES * MT)            // 100032
#define NEDGES 500000
#define HID    256
#define K2     512

typedef __bf16 bf16x8 __attribute__((ext_vector_type(8)));
typedef float  f32x4  __attribute__((ext_vector_type(4)));

__device__ __forceinline__ unsigned short f2bf(float f) {
    unsigned int u = __float_as_uint(f);
    u += 0x7FFFu + ((u >> 16) & 1u);
    return (unsigned short)(u >> 16);
}
__device__ __forceinline__ float bf2f(unsigned short s) {
    return __uint_as_float(((unsigned int)s) << 16);
}

// ---- W1 [256][512] fp32 -> Bsw bf16 fragment order (K=256, N=512) ----------
// B[k][j]: j<256 -> W1[j][k] (u weights); j>=256 -> W1[j-256][256+k] (v weights)
// Unit t=(kt*32+nt)*64+lane holds 8 bf16 along k: k=kt*32+(lane>>4)*8+jj, j=nt*16+(lane&15)
__global__ void cvt_w1uv(const float* __restrict__ W1, unsigned short* __restrict__ Bsw) {
    int t = blockIdx.x * 256 + threadIdx.x;                  // 8*32*64 = 16384 units
    if (t >= 8 * 32 * 64) return;
    int lane = t & 63, nt = (t >> 6) & 31, kt = t >> 11;
    int j = nt * 16 + (lane & 15);
    int k = kt * 32 + ((lane >> 4) << 3);
    const float* src = W1 + (size_t)(j & 255) * K2 + ((j >> 8) << 8) + k;
    union { unsigned short s[8]; uint4 v; } u;
#pragma unroll
    for (int jj = 0; jj < 8; ++jj) u.s[jj] = f2bf(src[jj]);
    ((uint4*)Bsw)[t] = u.v;
}

// ---- node GEMM v2: UV[n][j] = sum_k x[n][k] * B[k][j]  (+b1 folded into u) --
// M-tile 64, full N=512, K=256 staged once (32 KB LDS, fragment order, XOR
// swizzle phys = logical ^ ktl -> conflict-free writes AND reads).
// 256 thr / 4 waves; wave w covers N [w*128, w*128+128): mt=4 x nt=8, acc=128 VGPR.
__global__ __launch_bounds__(256, 2) void node_gemm2(
    const float* __restrict__ x,
    const unsigned short* __restrict__ Bsw,
    const float* __restrict__ b1,
    unsigned short* __restrict__ UV)
{
    __shared__ __align__(16) unsigned short Asw[2048 * 8];   // 32 KB
    const int tid  = threadIdx.x;
    const int lane = tid & 63;
    const int wave = tid >> 6;
    const int m0   = blockIdx.x * MT;

    // ---- stage A (64 rows x 256 k) fp32 -> bf16 fragment-swizzled LDS ----
    uint4* A4 = (uint4*)Asw;
    {
        const int k8 = tid & 31;                 // 8-elem k chunk
        const int mh = tid >> 5;                 // 0..7
#pragma unroll
        for (int i = 0; i < 8; ++i) {
            int m   = i * 8 + mh;                // 0..63
            int row = m0 + m;
            int rl  = row < NNODES ? row : 0;    // clamp pad rows (values unused)
            const float4* p = (const float4*)(x + (size_t)rl * 256 + k8 * 8);
            float4 a = p[0], b = p[1];
            union { unsigned short s[8]; uint4 v; } u;
            u.s[0] = f2bf(a.x); u.s[1] = f2bf(a.y); u.s[2] = f2bf(a.z); u.s[3] = f2bf(a.w);
            u.s[4] = f2bf(b.x); u.s[5] = f2bf(b.y); u.s[6] = f2bf(b.z); u.s[7] = f2bf(b.w);
            int logical = ((k8 >> 2) << 8) + ((m >> 4) << 6) + ((k8 & 3) << 4) + (m & 15);
            int phys    = logical ^ (k8 >> 2);   // XOR ktl into bank-group bits
            A4[phys] = u.v;
        }
    }
    __syncthreads();

    // ---- compute: 8 k-steps of 32; per wave 4 mt x 8 nt MFMAs ----
    f32x4 acc[4][8] = {};
    const bf16x8* A8 = (const bf16x8*)Asw;
    const bf16x8* B8 = (const bf16x8*)Bsw;
#pragma unroll
    for (int ks = 0; ks < 8; ++ks) {
        bf16x8 af[4];
#pragma unroll
        for (int mt = 0; mt < 4; ++mt)
            af[mt] = A8[((((ks * 4 + mt) << 6) + lane)) ^ ks];
        bf16x8 bfr[8];
#pragma unroll
        for (int nt = 0; nt < 8; ++nt)
            bfr[nt] = B8[((size_t)(ks * 32 + wave * 8 + nt)) * 64 + lane];
#pragma unroll
        for (int mt = 0; mt < 4; ++mt)
#pragma unroll
            for (int nt = 0; nt < 8; ++nt)
                acc[mt][nt] = __builtin_amdgcn_mfma_f32_16x16x32_bf16(
                    af[mt], bfr[nt], acc[mt][nt], 0, 0, 0);
    }

    // ---- epilogue: fold b1 into u columns, store bf16 ----
    float b1v[8];
#pragma unroll
    for (int nt = 0; nt < 8; ++nt) {
        int col = wave * 128 + nt * 16 + (lane & 15);
        b1v[nt] = (col < 256) ? b1[col] : 0.0f;
    }
#pragma unroll
    for (int mt = 0; mt < 4; ++mt) {
#pragma unroll
        for (int nt = 0; nt < 8; ++nt) {
            int col = wave * 128 + nt * 16 + (lane & 15);
#pragma unroll
            for (int r = 0; r < 4; ++r) {
                int row = m0 + mt * 16 + ((lane >> 4) << 2) + r;
                UV[(size_t)row * 512 + col] = f2bf(acc[mt][nt][r] + b1v[nt]);
            }
        }
    }
}

// ---- edge pass v2: 32 lanes/edge, 4 edges per group, b1 pre-folded ----------
// Block 256 thr = 8 groups; 32 edges/block; grid 15625 (exact, no bounds checks).
__global__ __launch_bounds__(256) void edge_out2(
    const unsigned short* __restrict__ UV,
    const int* __restrict__ ei,
    const float* __restrict__ W2,
    const float* __restrict__ b2,
    float* __restrict__ out)
{
    const int tid = threadIdx.x;
    const int q   = tid & 31;
    const int g   = tid >> 5;
    const long e  = (long)blockIdx.x * 32 + g * 4;

    // indices: 2 dwordx4 loads cover 4 edges
    int4 s4 = *(const int4*)(ei + e);
    int4 d4 = *(const int4*)(ei + NEDGES + e);

    const unsigned short* up = UV + q * 8;
    uint4 uu0 = *(const uint4*)(up + (size_t)s4.x * 512);
    uint4 vv0 = *(const uint4*)(up + (size_t)d4.x * 512 + 256);
    uint4 uu1 = *(const uint4*)(up + (size_t)s4.y * 512);
    uint4 vv1 = *(const uint4*)(up + (size_t)d4.y * 512 + 256);
    uint4 uu2 = *(const uint4*)(up + (size_t)s4.z * 512);
    uint4 vv2 = *(const uint4*)(up + (size_t)d4.z * 512 + 256);
    uint4 uu3 = *(const uint4*)(up + (size_t)s4.w * 512);
    uint4 vv3 = *(const uint4*)(up + (size_t)d4.w * 512 + 256);

    float w2v[8];
    {
        const float4* pw = (const float4*)W2 + q * 2;
        float4 c = pw[0], d = pw[1];
        w2v[0]=c.x; w2v[1]=c.y; w2v[2]=c.z; w2v[3]=c.w;
        w2v[4]=d.x; w2v[5]=d.y; w2v[6]=d.z; w2v[7]=d.w;
    }

    float z0 = 0.f, z1 = 0.f, z2 = 0.f, z3 = 0.f;
    const unsigned short* u0 = (const unsigned short*)&uu0;
    const unsigned short* v0 = (const unsigned short*)&vv0;
    const unsigned short* u1 = (const unsigned short*)&uu1;
    const unsigned short* v1 = (const unsigned short*)&vv1;
    const unsigned short* u2 = (const unsigned short*)&uu2;
    const unsigned short* v2 = (const unsigned short*)&vv2;
    const unsigned short* u3 = (const unsigned short*)&uu3;
    const unsigned short* v3 = (const unsigned short*)&vv3;
#pragma unroll
    for (int jj = 0; jj < 8; ++jj) {
        z0 = fmaf(fmaxf(bf2f(u0[jj]) + bf2f(v0[jj]), 0.f), w2v[jj], z0);
        z1 = fmaf(fmaxf(bf2f(u1[jj]) + bf2f(v1[jj]), 0.f), w2v[jj], z1);
        z2 = fmaf(fmaxf(bf2f(u2[jj]) + bf2f(v2[jj]), 0.f), w2v[jj], z2);
        z3 = fmaf(fmaxf(bf2f(u3[jj]) + bf2f(v3[jj]), 0.f), w2v[jj], z3);
    }
#pragma unroll
    for (int m = 1; m < 32; m <<= 1) {
        z0 += __shfl_xor(z0, m, 32);
        z1 += __shfl_xor(z1, m, 32);
        z2 += __shfl_xor(z2, m, 32);
        z3 += __shfl_xor(z3, m, 32);
    }
    if (q < 4) {
        float z = (q == 0) ? z0 : (q == 1) ? z1 : (q == 2) ? z2 : z3;
        out[e + q] = 1.0f / (1.0f + expf(-(z + b2[0])));
    }
}

// ======================= round-1 fallback path ==============================
__global__ void cvt_x_r1(const float* __restrict__ x, unsigned short* __restrict__ xb) {
    long i = (long)blockIdx.x * 256 + threadIdx.x;
    if (i >= (long)NNODES * (HID / 8)) return;
    const float4* p = (const float4*)x + i * 2;
    float4 a = p[0], b = p[1];
    union { unsigned short s[8]; uint4 v; } u;
    u.s[0] = f2bf(a.x); u.s[1] = f2bf(a.y); u.s[2] = f2bf(a.z); u.s[3] = f2bf(a.w);
    u.s[4] = f2bf(b.x); u.s[5] = f2bf(b.y); u.s[6] = f2bf(b.z); u.s[7] = f2bf(b.w);
    ((uint4*)xb)[i] = u.v;
}

__global__ void cvt_w1_r1(const float* __restrict__ W1, unsigned short* __restrict__ Bsw) {
    int t = blockIdx.x * 256 + threadIdx.x;
    if (t >= 16 * 16 * 64) return;
    int lane = t & 63, nt = (t >> 6) & 15, kt = t >> 10;
    int n = nt * 16 + (lane & 15);
    int k = kt * 32 + ((lane >> 4) << 3);
    const float* src = W1 + (size_t)n * K2 + k;
    union { unsigned short s[8]; uint4 v; } u;
#pragma unroll
    for (int j = 0; j < 8; ++j) u.s[j] = f2bf(src[j]);
    ((uint4*)Bsw)[t] = u.v;
}

template <bool USEBF>
__global__ __launch_bounds__(256) void edge_mlp_kernel(
    const unsigned short* __restrict__ xb, const float* __restrict__ xf,
    const int* __restrict__ ei, const unsigned short* __restrict__ Bsw,
    const float* __restrict__ b1, const float* __restrict__ W2,
    const float* __restrict__ b2, float* __restrict__ out)
{
    __shared__ __align__(16) unsigned short Asw[8 * 4 * 64 * 8];
    __shared__ float es[64];
    const int tid = threadIdx.x, lane = tid & 63, wave = tid >> 6;
    const int e0 = blockIdx.x * 64;
    if (tid < 64) es[tid] = 0.0f;
    f32x4 acc[4][4] = {};
    const bf16x8* A8 = (const bf16x8*)Asw;
    const bf16x8* B8 = (const bf16x8*)Bsw;
    for (int h = 0; h < 2; ++h) {
#pragma unroll
        for (int i = 0; i < 8; ++i) {
            int m = i * 8 + wave * 2 + (lane >> 5);
            int e = e0 + m;
            int ee = (e < NEDGES) ? e : 0;
            int node = ei[(size_t)h * NEDGES + ee];
            int chunk = lane & 31;
            uint4 v;
            if constexpr (USEBF) {
                v = *((const uint4*)(xb + ((size_t)node << 8) + (chunk << 3)));
            } else {
                const float4* p = (const float4*)(xf + ((size_t)node << 8) + (chunk << 3));
                float4 a = p[0], bq = p[1];
                union { unsigned short s[8]; uint4 v4; } u;
                u.s[0] = f2bf(a.x);  u.s[1] = f2bf(a.y);  u.s[2] = f2bf(a.z);  u.s[3] = f2bf(a.w);
                u.s[4] = f2bf(bq.x); u.s[5] = f2bf(bq.y); u.s[6] = f2bf(bq.z); u.s[7] = f2bf(bq.w);
                v = u.v4;
            }
            int ktl = chunk >> 2, qq = chunk & 3;
            int u16 = ((ktl * 4 + (m >> 4)) << 6) + (qq << 4) + (m & 15);
            u16 ^= (u16 >> 8) & 7;
            ((uint4*)Asw)[u16] = v;
        }
        __syncthreads();
#pragma unroll
        for (int kt = 0; kt < 8; ++kt) {
            bf16x8 af[4], bfr[4];
#pragma unroll
            for (int mt = 0; mt < 4; ++mt) {
                int u16 = ((kt * 4 + mt) << 6) + lane;
                u16 ^= (u16 >> 8) & 7;
                af[mt] = A8[u16];
            }
#pragma unroll
            for (int nt = 0; nt < 4; ++nt)
                bfr[nt] = B8[(((h * 8 + kt) << 4) + (wave << 2) + nt) * 64 + lane];
#pragma unroll
            for (int mt = 0; mt < 4; ++mt)
#pragma unroll
                for (int nt = 0; nt < 4; ++nt)
                    acc[mt][nt] = __builtin_amdgcn_mfma_f32_16x16x32_bf16(
                        af[mt], bfr[nt], acc[mt][nt], 0, 0, 0);
        }
        __syncthreads();
    }
    float w2v[4], b1v[4];
#pragma unroll
    for (int nt = 0; nt < 4; ++nt) {
        int n = (wave << 6) + (nt << 4) + (lane & 15);
        w2v[nt] = W2[n]; b1v[nt] = b1[n];
    }
#pragma unroll
    for (int mt = 0; mt < 4; ++mt) {
#pragma unroll
        for (int r = 0; r < 4; ++r) {
            float p = 0.0f;
#pragma unroll
            for (int nt = 0; nt < 4; ++nt) {
                float hv = acc[mt][nt][r] + b1v[nt];
                p = fmaf(fmaxf(hv, 0.0f), w2v[nt], p);
            }
            p += __shfl_xor(p, 1, 16);
            p += __shfl_xor(p, 2, 16);
            p += __shfl_xor(p, 4, 16);
            p += __shfl_xor(p, 8, 16);
            if ((lane & 15) == 0)
                atomicAdd(&es[(mt << 4) + ((lane >> 4) << 2) + r], p);
        }
    }
    __syncthreads();
    if (tid < 64) {
        int e = e0 + tid;
        if (e < NEDGES) out[e] = 1.0f / (1.0f + expf(-(es[tid] + b2[0])));
    }
}

// ============================== launch ======================================
extern "C" void kernel_launch(void* const* d_in, const int* in_sizes, int n_in,
                              void* d_out, int out_size, void* d_ws, size_t ws_size,
                              hipStream_t stream) {
    const float* x  = (const float*)d_in[0];
    const int*   ei = (const int*)d_in[1];
    const float* W1 = (const float*)d_in[2];
    const float* b1 = (const float*)d_in[3];
    const float* W2 = (const float*)d_in[4];
    const float* b2 = (const float*)d_in[5];
    float* out = (float*)d_out;

    const size_t BSW_BYTES = 1 << 18;                           // 256 KB
    const size_t UV_BYTES  = (size_t)NODESP * K2 * 2;           // ~102.5 MB
    const size_t NEED_A = BSW_BYTES + UV_BYTES;
    const size_t NEED_B = BSW_BYTES + (size_t)NNODES * HID * 2 + 1024;

    unsigned short* Bsw = (unsigned short*)d_ws;
    unsigned short* UV  = (unsigned short*)((char*)d_ws + BSW_BYTES);
    unsigned short* xb  = (unsigned short*)((char*)d_ws + BSW_BYTES);  // path B only

    if (ws_size >= NEED_A) {
        cvt_w1uv<<<64, 256, 0, stream>>>(W1, Bsw);
        node_gemm2<<<NTILES, 256, 0, stream>>>(x, Bsw, b1, UV);
        edge_out2<<<NEDGES / 32, 256, 0, stream>>>(UV, ei, W2, b2, out);
    } else if (ws_size >= NEED_B) {
        cvt_w1_r1<<<64, 256, 0, stream>>>(W1, Bsw);
        cvt_x_r1<<<(NNODES * (HID / 8) + 255) / 256, 256, 0, stream>>>(x, xb);
        edge_mlp_kernel<true><<<(NEDGES + 63) / 64, 256, 0, stream>>>(xb, x, ei, Bsw, b1, W2, b2, out);
    } else {
        cvt_w1_r1<<<64, 256, 0, stream>>>(W1, Bsw);
        edge_mlp_kernel<false><<<(NEDGES + 63) / 64, 256, 0, stream>>>(nullptr, x, ei, Bsw, b1, W2, b2, out);
    }
}

// Round 4
// 258.047 us; speedup vs baseline: 1.4616x; 1.0285x over previous
//
#include <hip/hip_runtime.h>
#include <math.h>

// Problem constants
#define NNODES 100000
#define MT     64
#define NTILES 1563                     // ceil(100000/64)
#define NODESP (NTILES * MT)            // 100032
#define NEDGES 500000
#define HID    256
#define K2     512

typedef _Float16 h8v __attribute__((ext_vector_type(8)));
typedef _Float16 h2v __attribute__((ext_vector_type(2)));
typedef __bf16   bf16x8 __attribute__((ext_vector_type(8)));
typedef float    f32x4  __attribute__((ext_vector_type(4)));

__device__ __forceinline__ unsigned short f2bf(float f) {
    unsigned int u = __float_as_uint(f);
    u += 0x7FFFu + ((u >> 16) & 1u);
    return (unsigned short)(u >> 16);
}
__device__ __forceinline__ float bf2f(unsigned short s) {
    return __uint_as_float(((unsigned int)s) << 16);
}

// ---- W1 [256][512] fp32 -> Bsw fp16 fragment order (K=256, N=512) ----------
// B[k][j]: j<256 -> W1[j][k] (u weights); j>=256 -> W1[j-256][256+k] (v weights)
// Unit t=(kt*32+nt)*64+lane holds 8 fp16 along k: k=kt*32+(lane>>4)*8+jj, j=nt*16+(lane&15)
__global__ void cvt_w1h(const float* __restrict__ W1, _Float16* __restrict__ Bsw) {
    int t = blockIdx.x * 256 + threadIdx.x;                  // 8*32*64 = 16384 units
    if (t >= 8 * 32 * 64) return;
    int lane = t & 63, nt = (t >> 6) & 31, kt = t >> 11;
    int j = nt * 16 + (lane & 15);
    int k = kt * 32 + ((lane >> 4) << 3);
    const float* src = W1 + (size_t)(j & 255) * K2 + ((j >> 8) << 8) + k;
    union { _Float16 s[8]; uint4 v; } u;
#pragma unroll
    for (int jj = 0; jj < 8; ++jj) u.s[jj] = (_Float16)src[jj];
    ((uint4*)Bsw)[t] = u.v;
}

// ---- node GEMM v3: UV[n][j] = sum_k x[n][k]*B[k][j] (+b1 into u cols) -------
// 512 thr / 8 waves. M=64, N=512 (wave w: cols w*64..w*64+63), K=256 one stage.
// acc 4x4 f32x4 = 64 regs/wave; launch_bounds(512,4) -> <=128 VGPR, 2 blocks/CU.
__global__ __launch_bounds__(512, 4) void node_gemm3(
    const float* __restrict__ x,
    const _Float16* __restrict__ Bsw,
    const float* __restrict__ b1,
    _Float16* __restrict__ UV)
{
    __shared__ __align__(16) _Float16 Asw[2048 * 8];         // 32 KB
    const int tid  = threadIdx.x;
    const int lane = tid & 63;
    const int wave = tid >> 6;
    const int m0   = blockIdx.x * MT;

    // ---- stage A (64 rows x 256 k) fp32 -> fp16, fragment-swizzled ----
    uint4* A4 = (uint4*)Asw;
    {
        const int k8 = tid & 31;                 // 8-elem k chunk 0..31
        const int mh = tid >> 5;                 // 0..15
        const int ktl = k8 >> 2, q = k8 & 3;
#pragma unroll
        for (int i = 0; i < 4; ++i) {
            int m   = i * 16 + mh;               // 0..63
            int row = m0 + m;
            int rl  = row < NNODES ? row : 0;
            const float4* p = (const float4*)(x + (size_t)rl * 256 + k8 * 8);
            float4 a = p[0], b = p[1];
            union { _Float16 s[8]; uint4 v; } u;
            u.s[0] = (_Float16)a.x; u.s[1] = (_Float16)a.y;
            u.s[2] = (_Float16)a.z; u.s[3] = (_Float16)a.w;
            u.s[4] = (_Float16)b.x; u.s[5] = (_Float16)b.y;
            u.s[6] = (_Float16)b.z; u.s[7] = (_Float16)b.w;
            int logical = (ktl << 8) + ((m >> 4) << 6) + (q << 4) + (m & 15);
            A4[logical ^ ktl] = u.v;
        }
    }
    __syncthreads();

    // ---- compute: 8 k-steps; per wave 4 mt x 4 nt MFMAs ----
    f32x4 acc[4][4] = {};
    const h8v* A8 = (const h8v*)Asw;
    const h8v* B8 = (const h8v*)Bsw;
#pragma unroll
    for (int ks = 0; ks < 8; ++ks) {
        h8v af[4], bfr[4];
#pragma unroll
        for (int mt = 0; mt < 4; ++mt)
            af[mt] = A8[(((ks * 4 + mt) << 6) + lane) ^ ks];
#pragma unroll
        for (int nt = 0; nt < 4; ++nt)
            bfr[nt] = B8[((size_t)(ks * 32 + wave * 4 + nt)) * 64 + lane];
#pragma unroll
        for (int mt = 0; mt < 4; ++mt)
#pragma unroll
            for (int nt = 0; nt < 4; ++nt)
                acc[mt][nt] = __builtin_amdgcn_mfma_f32_16x16x32_f16(
                    af[mt], bfr[nt], acc[mt][nt], 0, 0, 0);
    }

    // ---- epilogue: fold b1 into u columns (cols<256), store fp16 ----
    float b1v[4];
#pragma unroll
    for (int nt = 0; nt < 4; ++nt) {
        int col = wave * 64 + nt * 16 + (lane & 15);
        b1v[nt] = (col < 256) ? b1[col] : 0.0f;
    }
#pragma unroll
    for (int mt = 0; mt < 4; ++mt) {
#pragma unroll
        for (int nt = 0; nt < 4; ++nt) {
            int col = wave * 64 + nt * 16 + (lane & 15);
#pragma unroll
            for (int r = 0; r < 4; ++r) {
                int row = m0 + mt * 16 + ((lane >> 4) << 2) + r;
                UV[(size_t)row * 512 + col] = (_Float16)(acc[mt][nt][r] + b1v[nt]);
            }
        }
    }
}

// ---- edge pass v3: packed fp16. 32 lanes/edge, 4 edges/group ---------------
// Block 256 thr = 8 groups; 32 edges/block; grid 15625 exact.
__global__ __launch_bounds__(256) void edge_out3(
    const _Float16* __restrict__ UV,
    const int* __restrict__ ei,
    const float* __restrict__ W2,
    const float* __restrict__ b2,
    float* __restrict__ out)
{
    const int tid = threadIdx.x;
    const int q   = tid & 31;
    const int g   = tid >> 5;
    const long e  = (long)blockIdx.x * 32 + g * 4;

    int4 s4 = *(const int4*)(ei + e);
    int4 d4 = *(const int4*)(ei + NEDGES + e);

    // W2 fp32 -> 4 packed fp16 pairs (elems q*8..q*8+7)
    h2v w2h[4];
    {
        const float4* pw = (const float4*)W2 + q * 2;
        float4 c = pw[0], d = pw[1];
        w2h[0] = h2v{(_Float16)c.x, (_Float16)c.y};
        w2h[1] = h2v{(_Float16)c.z, (_Float16)c.w};
        w2h[2] = h2v{(_Float16)d.x, (_Float16)d.y};
        w2h[3] = h2v{(_Float16)d.z, (_Float16)d.w};
    }

    union U8 { uint4 v; h2v h[4]; };
    const _Float16* up = UV + q * 8;

    U8 uu[4], vv[4];
    uu[0].v = *(const uint4*)(up + (size_t)s4.x * 512);
    vv[0].v = *(const uint4*)(up + (size_t)d4.x * 512 + 256);
    uu[1].v = *(const uint4*)(up + (size_t)s4.y * 512);
    vv[1].v = *(const uint4*)(up + (size_t)d4.y * 512 + 256);
    uu[2].v = *(const uint4*)(up + (size_t)s4.z * 512);
    vv[2].v = *(const uint4*)(up + (size_t)d4.z * 512 + 256);
    uu[3].v = *(const uint4*)(up + (size_t)s4.w * 512);
    vv[3].v = *(const uint4*)(up + (size_t)d4.w * 512 + 256);

    const h2v zz = {(_Float16)0.0f, (_Float16)0.0f};
    float z[4] = {0.f, 0.f, 0.f, 0.f};
#pragma unroll
    for (int ed = 0; ed < 4; ++ed) {
#pragma unroll
        for (int p = 0; p < 4; ++p) {
            h2v h = uu[ed].h[p] + vv[ed].h[p];               // v_pk_add_f16
            h = __builtin_elementwise_max(h, zz);            // v_pk_max_f16
            z[ed] = __builtin_amdgcn_fdot2(h, w2h[p], z[ed], false);
        }
    }
#pragma unroll
    for (int m = 1; m < 32; m <<= 1) {
        z[0] += __shfl_xor(z[0], m, 32);
        z[1] += __shfl_xor(z[1], m, 32);
        z[2] += __shfl_xor(z[2], m, 32);
        z[3] += __shfl_xor(z[3], m, 32);
    }
    if (q < 4) {
        float zq = (q == 0) ? z[0] : (q == 1) ? z[1] : (q == 2) ? z[2] : z[3];
        out[e + q] = 1.0f / (1.0f + expf(-(zq + b2[0])));
    }
}

// ======================= minimal fallback (tiny ws) =========================
__global__ void cvt_w1_r1(const float* __restrict__ W1, unsigned short* __restrict__ Bsw) {
    int t = blockIdx.x * 256 + threadIdx.x;
    if (t >= 16 * 16 * 64) return;
    int lane = t & 63, nt = (t >> 6) & 15, kt = t >> 10;
    int n = nt * 16 + (lane & 15);
    int k = kt * 32 + ((lane >> 4) << 3);
    const float* src = W1 + (size_t)n * K2 + k;
    union { unsigned short s[8]; uint4 v; } u;
#pragma unroll
    for (int j = 0; j < 8; ++j) u.s[j] = f2bf(src[j]);
    ((uint4*)Bsw)[t] = u.v;
}

__global__ __launch_bounds__(256) void edge_mlp_fb(
    const float* __restrict__ xf, const int* __restrict__ ei,
    const unsigned short* __restrict__ Bsw, const float* __restrict__ b1,
    const float* __restrict__ W2, const float* __restrict__ b2,
    float* __restrict__ out)
{
    __shared__ __align__(16) unsigned short Asw[8 * 4 * 64 * 8];
    __shared__ float es[64];
    const int tid = threadIdx.x, lane = tid & 63, wave = tid >> 6;
    const int e0 = blockIdx.x * 64;
    if (tid < 64) es[tid] = 0.0f;
    f32x4 acc[4][4] = {};
    const bf16x8* A8 = (const bf16x8*)Asw;
    const bf16x8* B8 = (const bf16x8*)Bsw;
    for (int h = 0; h < 2; ++h) {
#pragma unroll
        for (int i = 0; i < 8; ++i) {
            int m = i * 8 + wave * 2 + (lane >> 5);
            int e = e0 + m;
            int ee = (e < NEDGES) ? e : 0;
            int node = ei[(size_t)h * NEDGES + ee];
            int chunk = lane & 31;
            const float4* p = (const float4*)(xf + ((size_t)node << 8) + (chunk << 3));
            float4 a = p[0], bq = p[1];
            union { unsigned short s[8]; uint4 v4; } u;
            u.s[0] = f2bf(a.x);  u.s[1] = f2bf(a.y);  u.s[2] = f2bf(a.z);  u.s[3] = f2bf(a.w);
            u.s[4] = f2bf(bq.x); u.s[5] = f2bf(bq.y); u.s[6] = f2bf(bq.z); u.s[7] = f2bf(bq.w);
            int ktl = chunk >> 2, qq = chunk & 3;
            int u16 = ((ktl * 4 + (m >> 4)) << 6) + (qq << 4) + (m & 15);
            u16 ^= (u16 >> 8) & 7;
            ((uint4*)Asw)[u16] = u.v4;
        }
        __syncthreads();
#pragma unroll
        for (int kt = 0; kt < 8; ++kt) {
            bf16x8 af[4], bfr[4];
#pragma unroll
            for (int mt = 0; mt < 4; ++mt) {
                int u16 = ((kt * 4 + mt) << 6) + lane;
                u16 ^= (u16 >> 8) & 7;
                af[mt] = A8[u16];
            }
#pragma unroll
            for (int nt = 0; nt < 4; ++nt)
                bfr[nt] = B8[(((h * 8 + kt) << 4) + (wave << 2) + nt) * 64 + lane];
#pragma unroll
            for (int mt = 0; mt < 4; ++mt)
#pragma unroll
                for (int nt = 0; nt < 4; ++nt)
                    acc[mt][nt] = __builtin_amdgcn_mfma_f32_16x16x32_bf16(
                        af[mt], bfr[nt], acc[mt][nt], 0, 0, 0);
        }
        __syncthreads();
    }
    float w2v[4], b1v[4];
#pragma unroll
    for (int nt = 0; nt < 4; ++nt) {
        int n = (wave << 6) + (nt << 4) + (lane & 15);
        w2v[nt] = W2[n]; b1v[nt] = b1[n];
    }
#pragma unroll
    for (int mt = 0; mt < 4; ++mt) {
#pragma unroll
        for (int r = 0; r < 4; ++r) {
            float p = 0.0f;
#pragma unroll
            for (int nt = 0; nt < 4; ++nt) {
                float hv = acc[mt][nt][r] + b1v[nt];
                p = fmaf(fmaxf(hv, 0.0f), w2v[nt], p);
            }
            p += __shfl_xor(p, 1, 16);
            p += __shfl_xor(p, 2, 16);
            p += __shfl_xor(p, 4, 16);
            p += __shfl_xor(p, 8, 16);
            if ((lane & 15) == 0)
                atomicAdd(&es[(mt << 4) + ((lane >> 4) << 2) + r], p);
        }
    }
    __syncthreads();
    if (tid < 64) {
        int e = e0 + tid;
        if (e < NEDGES) out[e] = 1.0f / (1.0f + expf(-(es[tid] + b2[0])));
    }
}

// ============================== launch ======================================
extern "C" void kernel_launch(void* const* d_in, const int* in_sizes, int n_in,
                              void* d_out, int out_size, void* d_ws, size_t ws_size,
                              hipStream_t stream) {
    const float* x  = (const float*)d_in[0];
    const int*   ei = (const int*)d_in[1];
    const float* W1 = (const float*)d_in[2];
    const float* b1 = (const float*)d_in[3];
    const float* W2 = (const float*)d_in[4];
    const float* b2 = (const float*)d_in[5];
    float* out = (float*)d_out;

    const size_t BSW_BYTES = 1 << 18;                           // 256 KB
    const size_t UV_BYTES  = (size_t)NODESP * K2 * 2;           // ~102.5 MB
    const size_t NEED_A = BSW_BYTES + UV_BYTES;

    if (ws_size >= NEED_A) {
        _Float16* Bsw = (_Float16*)d_ws;
        _Float16* UV  = (_Float16*)((char*)d_ws + BSW_BYTES);
        cvt_w1h<<<64, 256, 0, stream>>>(W1, Bsw);
        node_gemm3<<<NTILES, 512, 0, stream>>>(x, Bsw, b1, UV);
        edge_out3<<<NEDGES / 32, 256, 0, stream>>>(UV, ei, W2, b2, out);
    } else {
        unsigned short* Bsw = (unsigned short*)d_ws;
        cvt_w1_r1<<<64, 256, 0, stream>>>(W1, Bsw);
        edge_mlp_fb<<<(NEDGES + 63) / 64, 256, 0, stream>>>(x, ei, Bsw, b1, W2, b2, out);
    }
}

// Round 5
// 253.376 us; speedup vs baseline: 1.4886x; 1.0184x over previous
//
#include <hip/hip_runtime.h>
#include <math.h>

// Problem constants
#define NNODES 100000
#define MT     64
#define NTILES 1563                     // ceil(100000/64)
#define NODESP (NTILES * MT)            // 100032
#define NEDGES 500000
#define HID    256
#define K2     512
#define GEMM_GRID 256

typedef _Float16 h8v __attribute__((ext_vector_type(8)));
typedef _Float16 h2v __attribute__((ext_vector_type(2)));
typedef __bf16   bf16x8 __attribute__((ext_vector_type(8)));
typedef float    f32x4  __attribute__((ext_vector_type(4)));

__device__ __forceinline__ unsigned short f2bf(float f) {
    unsigned int u = __float_as_uint(f);
    u += 0x7FFFu + ((u >> 16) & 1u);
    return (unsigned short)(u >> 16);
}

// ---- W1 [256][512] fp32 -> Bsw fp16 fragment order (K=256, N=512) ----------
// B[k][j]: j<256 -> W1[j][k] (u weights); j>=256 -> W1[j-256][256+k] (v weights)
// Unit t=(kt*32+nt)*64+lane holds 8 fp16 along k: k=kt*32+(lane>>4)*8+jj, j=nt*16+(lane&15)
__global__ void cvt_w1h(const float* __restrict__ W1, _Float16* __restrict__ Bsw) {
    int t = blockIdx.x * 256 + threadIdx.x;                  // 8*32*64 = 16384 units
    if (t >= 8 * 32 * 64) return;
    int lane = t & 63, nt = (t >> 6) & 31, kt = t >> 11;
    int j = nt * 16 + (lane & 15);
    int k = kt * 32 + ((lane >> 4) << 3);
    const float* src = W1 + (size_t)(j & 255) * K2 + ((j >> 8) << 8) + k;
    union { _Float16 s[8]; uint4 v; } u;
#pragma unroll
    for (int jj = 0; jj < 8; ++jj) u.s[jj] = (_Float16)src[jj];
    ((uint4*)Bsw)[t] = u.v;
}

// ---- W2 [256] fp32 -> permuted order matching UV's stored column order -----
// stored index t = w*64 + i*4 + nt  <->  hidden col = w*64 + nt*16 + i
__global__ void cvt_w2p(const float* __restrict__ W2, float* __restrict__ w2p) {
    int t = threadIdx.x;                                     // one block of 256
    int i = (t >> 2) & 15, nt = t & 3;
    w2p[t] = W2[(t & ~63) | (nt * 16 + i)];
}

// ---- node GEMM v4: persistent blocks, B entirely in registers --------------
// Grid 256 x 512 thr (8 waves). Wave w owns cols [w*64, w*64+64): B-frags for
// full K=256 = 32 x h8v = 128 VGPRs, loaded ONCE. Each block loops over
// M-tiles (64 rows): stage A fp32->fp16 into XOR-swizzled LDS, 8 ks x 16 MFMA,
// store UV in permuted-column order (coalesced dwordx2; edge pass uses w2p).
__global__ __launch_bounds__(512, 2) void node_gemm4(
    const float* __restrict__ x,
    const _Float16* __restrict__ Bsw,
    const float* __restrict__ b1,
    _Float16* __restrict__ UV)
{
    __shared__ __align__(16) _Float16 Asw[2048 * 8];         // 32 KB
    const int tid  = threadIdx.x;
    const int lane = tid & 63;
    const int wave = tid >> 6;

    // ---- B into registers (once) ----
    const h8v* B8 = (const h8v*)Bsw;
    h8v barr[8][4];
#pragma unroll
    for (int ks = 0; ks < 8; ++ks)
#pragma unroll
        for (int nt = 0; nt < 4; ++nt)
            barr[ks][nt] = B8[((size_t)(ks * 32 + wave * 4 + nt)) * 64 + lane];

    float b1v[4];
#pragma unroll
    for (int nt = 0; nt < 4; ++nt) {
        int col = wave * 64 + nt * 16 + (lane & 15);         // true hidden col
        b1v[nt] = (col < 256) ? b1[col] : 0.0f;
    }

    uint4* A4 = (uint4*)Asw;
    const h8v* A8 = (const h8v*)Asw;
    const int k8  = tid & 31;                                // 8-elem k chunk
    const int mh  = tid >> 5;                                // 0..15
    const int ktl = k8 >> 2, q = k8 & 3;

    auto stage = [&](int tile) {
#pragma unroll
        for (int i = 0; i < 4; ++i) {
            int m   = i * 16 + mh;                           // 0..63
            int row = tile * MT + m;
            int rl  = row < NNODES ? row : 0;
            const float4* p = (const float4*)(x + (size_t)rl * 256 + k8 * 8);
            float4 a = p[0], b = p[1];
            union { _Float16 s[8]; uint4 v; } u;
            u.s[0] = (_Float16)a.x; u.s[1] = (_Float16)a.y;
            u.s[2] = (_Float16)a.z; u.s[3] = (_Float16)a.w;
            u.s[4] = (_Float16)b.x; u.s[5] = (_Float16)b.y;
            u.s[6] = (_Float16)b.z; u.s[7] = (_Float16)b.w;
            int logical = (ktl << 8) + ((m >> 4) << 6) + (q << 4) + (m & 15);
            A4[logical ^ ktl] = u.v;
        }
    };

    f32x4 acc[4][4] = {};
    int tile = blockIdx.x;
    if (tile >= NTILES) return;
    stage(tile);
    __syncthreads();

    while (true) {
        // ---- compute: 8 k-steps, B from registers ----
#pragma unroll
        for (int ks = 0; ks < 8; ++ks) {
            h8v af[4];
#pragma unroll
            for (int mt = 0; mt < 4; ++mt)
                af[mt] = A8[(((ks * 4 + mt) << 6) + lane) ^ ks];
#pragma unroll
            for (int mt = 0; mt < 4; ++mt)
#pragma unroll
                for (int nt = 0; nt < 4; ++nt)
                    acc[mt][nt] = __builtin_amdgcn_mfma_f32_16x16x32_f16(
                        af[mt], barr[ks][nt], acc[mt][nt], 0, 0, 0);
        }
        __syncthreads();                                     // all done reading Asw

        int next = tile + GEMM_GRID;
        if (next < NTILES) stage(next);                      // overlap with stores

        // ---- store tile: permuted cols -> coalesced dwordx2; fold b1 ----
#pragma unroll
        for (int mt = 0; mt < 4; ++mt) {
#pragma unroll
            for (int r = 0; r < 4; ++r) {
                int row = tile * MT + mt * 16 + ((lane >> 4) << 2) + r;
                union { _Float16 h[4]; uint2 v; } pk;
#pragma unroll
                for (int nt = 0; nt < 4; ++nt)
                    pk.h[nt] = (_Float16)(acc[mt][nt][r] + b1v[nt]);
                *(uint2*)(UV + (size_t)row * 512 + wave * 64 + (lane & 15) * 4) = pk.v;
            }
        }
#pragma unroll
        for (int mt = 0; mt < 4; ++mt)
#pragma unroll
            for (int nt = 0; nt < 4; ++nt)
                acc[mt][nt] = f32x4{0.f, 0.f, 0.f, 0.f};

        if (next >= NTILES) break;
        tile = next;
        __syncthreads();                                     // staged data visible
    }
}

// ---- edge pass: packed fp16, w2 pre-permuted to UV's stored order ----------
__global__ __launch_bounds__(256) void edge_out4(
    const _Float16* __restrict__ UV,
    const int* __restrict__ ei,
    const float* __restrict__ w2p,
    const float* __restrict__ b2,
    float* __restrict__ out)
{
    const int tid = threadIdx.x;
    const int q   = tid & 31;
    const int g   = tid >> 5;
    const long e  = (long)blockIdx.x * 32 + g * 4;

    int4 s4 = *(const int4*)(ei + e);
    int4 d4 = *(const int4*)(ei + NEDGES + e);

    h2v w2h[4];
    {
        const float4* pw = (const float4*)w2p + q * 2;
        float4 c = pw[0], d = pw[1];
        w2h[0] = h2v{(_Float16)c.x, (_Float16)c.y};
        w2h[1] = h2v{(_Float16)c.z, (_Float16)c.w};
        w2h[2] = h2v{(_Float16)d.x, (_Float16)d.y};
        w2h[3] = h2v{(_Float16)d.z, (_Float16)d.w};
    }

    union U8 { uint4 v; h2v h[4]; };
    const _Float16* up = UV + q * 8;

    U8 uu[4], vv[4];
    uu[0].v = *(const uint4*)(up + (size_t)s4.x * 512);
    vv[0].v = *(const uint4*)(up + (size_t)d4.x * 512 + 256);
    uu[1].v = *(const uint4*)(up + (size_t)s4.y * 512);
    vv[1].v = *(const uint4*)(up + (size_t)d4.y * 512 + 256);
    uu[2].v = *(const uint4*)(up + (size_t)s4.z * 512);
    vv[2].v = *(const uint4*)(up + (size_t)d4.z * 512 + 256);
    uu[3].v = *(const uint4*)(up + (size_t)s4.w * 512);
    vv[3].v = *(const uint4*)(up + (size_t)d4.w * 512 + 256);

    const h2v zz = {(_Float16)0.0f, (_Float16)0.0f};
    float z[4] = {0.f, 0.f, 0.f, 0.f};
#pragma unroll
    for (int ed = 0; ed < 4; ++ed) {
#pragma unroll
        for (int p = 0; p < 4; ++p) {
            h2v h = uu[ed].h[p] + vv[ed].h[p];               // v_pk_add_f16
            h = __builtin_elementwise_max(h, zz);            // v_pk_max_f16
            z[ed] = __builtin_amdgcn_fdot2(h, w2h[p], z[ed], false);
        }
    }
#pragma unroll
    for (int m = 1; m < 32; m <<= 1) {
        z[0] += __shfl_xor(z[0], m, 32);
        z[1] += __shfl_xor(z[1], m, 32);
        z[2] += __shfl_xor(z[2], m, 32);
        z[3] += __shfl_xor(z[3], m, 32);
    }
    if (q < 4) {
        float zq = (q == 0) ? z[0] : (q == 1) ? z[1] : (q == 2) ? z[2] : z[3];
        out[e + q] = 1.0f / (1.0f + expf(-(zq + b2[0])));
    }
}

// ======================= minimal fallback (tiny ws) =========================
__global__ void cvt_w1_r1(const float* __restrict__ W1, unsigned short* __restrict__ Bsw) {
    int t = blockIdx.x * 256 + threadIdx.x;
    if (t >= 16 * 16 * 64) return;
    int lane = t & 63, nt = (t >> 6) & 15, kt = t >> 10;
    int n = nt * 16 + (lane & 15);
    int k = kt * 32 + ((lane >> 4) << 3);
    const float* src = W1 + (size_t)n * K2 + k;
    union { unsigned short s[8]; uint4 v; } u;
#pragma unroll
    for (int j = 0; j < 8; ++j) u.s[j] = f2bf(src[j]);
    ((uint4*)Bsw)[t] = u.v;
}

__global__ __launch_bounds__(256) void edge_mlp_fb(
    const float* __restrict__ xf, const int* __restrict__ ei,
    const unsigned short* __restrict__ Bsw, const float* __restrict__ b1,
    const float* __restrict__ W2, const float* __restrict__ b2,
    float* __restrict__ out)
{
    __shared__ __align__(16) unsigned short Asw[8 * 4 * 64 * 8];
    __shared__ float es[64];
    const int tid = threadIdx.x, lane = tid & 63, wave = tid >> 6;
    const int e0 = blockIdx.x * 64;
    if (tid < 64) es[tid] = 0.0f;
    f32x4 acc[4][4] = {};
    const bf16x8* A8 = (const bf16x8*)Asw;
    const bf16x8* B8 = (const bf16x8*)Bsw;
    for (int h = 0; h < 2; ++h) {
#pragma unroll
        for (int i = 0; i < 8; ++i) {
            int m = i * 8 + wave * 2 + (lane >> 5);
            int e = e0 + m;
            int ee = (e < NEDGES) ? e : 0;
            int node = ei[(size_t)h * NEDGES + ee];
            int chunk = lane & 31;
            const float4* p = (const float4*)(xf + ((size_t)node << 8) + (chunk << 3));
            float4 a = p[0], bq = p[1];
            union { unsigned short s[8]; uint4 v4; } u;
            u.s[0] = f2bf(a.x);  u.s[1] = f2bf(a.y);  u.s[2] = f2bf(a.z);  u.s[3] = f2bf(a.w);
            u.s[4] = f2bf(bq.x); u.s[5] = f2bf(bq.y); u.s[6] = f2bf(bq.z); u.s[7] = f2bf(bq.w);
            int ktl = chunk >> 2, qq = chunk & 3;
            int u16 = ((ktl * 4 + (m >> 4)) << 6) + (qq << 4) + (m & 15);
            u16 ^= (u16 >> 8) & 7;
            ((uint4*)Asw)[u16] = u.v4;
        }
        __syncthreads();
#pragma unroll
        for (int kt = 0; kt < 8; ++kt) {
            bf16x8 af[4], bfr[4];
#pragma unroll
            for (int mt = 0; mt < 4; ++mt) {
                int u16 = ((kt * 4 + mt) << 6) + lane;
                u16 ^= (u16 >> 8) & 7;
                af[mt] = A8[u16];
            }
#pragma unroll
            for (int nt = 0; nt < 4; ++nt)
                bfr[nt] = B8[(((h * 8 + kt) << 4) + (wave << 2) + nt) * 64 + lane];
#pragma unroll
            for (int mt = 0; mt < 4; ++mt)
#pragma unroll
                for (int nt = 0; nt < 4; ++nt)
                    acc[mt][nt] = __builtin_amdgcn_mfma_f32_16x16x32_bf16(
                        af[mt], bfr[nt], acc[mt][nt], 0, 0, 0);
        }
        __syncthreads();
    }
    float w2v[4], b1v[4];
#pragma unroll
    for (int nt = 0; nt < 4; ++nt) {
        int n = (wave << 6) + (nt << 4) + (lane & 15);
        w2v[nt] = W2[n]; b1v[nt] = b1[n];
    }
#pragma unroll
    for (int mt = 0; mt < 4; ++mt) {
#pragma unroll
        for (int r = 0; r < 4; ++r) {
            float p = 0.0f;
#pragma unroll
            for (int nt = 0; nt < 4; ++nt) {
                float hv = acc[mt][nt][r] + b1v[nt];
                p = fmaf(fmaxf(hv, 0.0f), w2v[nt], p);
            }
            p += __shfl_xor(p, 1, 16);
            p += __shfl_xor(p, 2, 16);
            p += __shfl_xor(p, 4, 16);
            p += __shfl_xor(p, 8, 16);
            if ((lane & 15) == 0)
                atomicAdd(&es[(mt << 4) + ((lane >> 4) << 2) + r], p);
        }
    }
    __syncthreads();
    if (tid < 64) {
        int e = e0 + tid;
        if (e < NEDGES) out[e] = 1.0f / (1.0f + expf(-(es[tid] + b2[0])));
    }
}

// ============================== launch ======================================
extern "C" void kernel_launch(void* const* d_in, const int* in_sizes, int n_in,
                              void* d_out, int out_size, void* d_ws, size_t ws_size,
                              hipStream_t stream) {
    const float* x  = (const float*)d_in[0];
    const int*   ei = (const int*)d_in[1];
    const float* W1 = (const float*)d_in[2];
    const float* b1 = (const float*)d_in[3];
    const float* W2 = (const float*)d_in[4];
    const float* b2 = (const float*)d_in[5];
    float* out = (float*)d_out;

    const size_t BSW_BYTES = 1 << 18;                           // 256 KB
    const size_t W2P_BYTES = 4096;
    const size_t UV_BYTES  = (size_t)NODESP * K2 * 2;           // ~102.5 MB
    const size_t NEED_A = BSW_BYTES + W2P_BYTES + UV_BYTES;

    if (ws_size >= NEED_A) {
        _Float16* Bsw = (_Float16*)d_ws;
        float*    w2p = (float*)((char*)d_ws + BSW_BYTES);
        _Float16* UV  = (_Float16*)((char*)d_ws + BSW_BYTES + W2P_BYTES);
        cvt_w1h<<<64, 256, 0, stream>>>(W1, Bsw);
        cvt_w2p<<<1, 256, 0, stream>>>(W2, w2p);
        node_gemm4<<<GEMM_GRID, 512, 0, stream>>>(x, Bsw, b1, UV);
        edge_out4<<<NEDGES / 32, 256, 0, stream>>>(UV, ei, w2p, b2, out);
    } else {
        unsigned short* Bsw = (unsigned short*)d_ws;
        cvt_w1_r1<<<64, 256, 0, stream>>>(W1, Bsw);
        edge_mlp_fb<<<(NEDGES + 63) / 64, 256, 0, stream>>>(x, ei, Bsw, b1, W2, b2, out);
    }
}